// Round 8
// baseline (280.105 us; speedup 1.0000x reference)
//
#include <hip/hip_runtime.h>
#include <cstddef>

#define B 64
#define NC 10
#define L 900
#define STASH_STRIDE 36000  // bytes: one full f32 out_map image slice (9000 floats)

// ---- K prep_tables: block 0 = qkv/score tables; blocks 1.. = weight prep --
// wt0[r][32]: conv1 (r=ic*9+kk), wt2[r][64]: conv2, wt1[r][32]: dec1
// flipped+transposed+BN-scaled, bias1[32] = db*s + bnb
__global__ void k_prep_tables(const float* __restrict__ embed,
                              const float* __restrict__ ipw,
                              const float* __restrict__ ipb,
                              const float* __restrict__ cw1,
                              const float* __restrict__ cw2,
                              const float* __restrict__ dw,
                              const float* __restrict__ db,
                              const float* __restrict__ bng,
                              const float* __restrict__ bnb,
                              float* __restrict__ ve_g, float* __restrict__ S_g,
                              float* __restrict__ wt0, float* __restrict__ wt2,
                              float* __restrict__ wt1, float* __restrict__ bias1) {
  int t = threadIdx.x;
  if (blockIdx.x == 0) {
    __shared__ float emb[640], q[640], k[640];
    for (int i = t; i < 640; i += 256) emb[i] = embed[i];
    __syncthreads();
    for (int row = t; row < 192; row += 256) {
      int which = row >> 6, d = row & 63;
      for (int c = 0; c < 10; ++c) {
        float acc = ipb[row];
        for (int j = 0; j < 64; ++j) acc += emb[c * 64 + j] * ipw[row * 64 + j];
        if (which == 0) q[c * 64 + d] = acc;
        else if (which == 1) k[c * 64 + d] = acc;
        else ve_g[c * 64 + d] = acc;
      }
    }
    __syncthreads();
    for (int i = t; i < 400; i += 256) {
      int h = i / 100, r = i % 100, cq = r / 10, ck = r % 10;
      float acc = 0.f;
      for (int e = 0; e < 16; ++e)
        acc += q[cq * 64 + h * 16 + e] * k[ck * 64 + h * 16 + e];
      S_g[i] = acc * 0.25f;
    }
    return;
  }
  int i = (blockIdx.x - 1) * 256 + t;
  if (i < 2880) {
    int r = i / 32, oc = i % 32;
    wt0[r * 32 + oc] = cw1[oc * 90 + r];
  } else if (i < 2880 + 18432) {
    int e = i - 2880, r = e / 64, oc = e % 64;
    wt2[r * 64 + oc] = cw2[oc * 288 + r];
  } else if (i < 2880 + 18432 + 18432) {
    int e = i - 2880 - 18432, r = e / 32, oc = e % 32;
    int ic = r / 9, kk = r % 9, ky = kk / 3, kx = kk % 3;
    float s = bng[oc] / sqrtf(1.f + 1e-5f);
    wt1[r * 32 + oc] = dw[((ic * 32 + oc) * 3 + (2 - ky)) * 3 + (2 - kx)] * s;
  } else if (i < 39744 + 32) {
    int oc = i - 39744;
    float s = bng[oc] / sqrtf(1.f + 1e-5f);
    bias1[oc] = db[oc] * s + bnb[oc];
  }
}

// ---- K idxattn: per-image argmax + hist + softmax + CW + ctx + AT ---------
// Also writes idx + CW into the stash slice.
__global__ void k_idxattn(const float* __restrict__ g, const float* __restrict__ S,
                          const float* __restrict__ ve,
                          const float* __restrict__ opw, const float* __restrict__ opb,
                          int* __restrict__ idx_g, float* __restrict__ CW,
                          float* __restrict__ AT, unsigned char* __restrict__ stash) {
  int b = blockIdx.x, t = threadIdx.x;  // 256 threads
  unsigned char* sl = stash + (size_t)b * STASH_STRIDE;
  int* sidx = (int*)sl;
  float* scw = (float*)(sl + 3640);
  __shared__ float A[4][10][10];
  __shared__ float cf[10];
  __shared__ float ctx[10][64];
  __shared__ int hist[10];
  if (t < 10) hist[t] = 0;
  __syncthreads();
  const float* gb = g + (size_t)b * NC * L;
  for (int p = t; p < 900; p += 256) {
    float best = gb[p]; int bi = 0;
    for (int c = 1; c < NC; ++c) {
      float v = gb[c * L + p];
      if (v > best) { best = v; bi = c; }
    }
    idx_g[b * L + p] = bi;
    sidx[p] = bi;
    atomicAdd(&hist[bi], 1);
  }
  __syncthreads();
  if (t < 10) cf[t] = (float)hist[t];
  __syncthreads();
  if (t < 40) {
    int h = t / 10, cq = t % 10;
    const float* Sr = S + (h * 10 + cq) * 10;
    float m = -1e30f;
    for (int c = 0; c < 10; ++c) if (cf[c] > 0.f) m = fmaxf(m, Sr[c]);
    float e[10]; float Z = 0.f;
    for (int c = 0; c < 10; ++c) { e[c] = expf(Sr[c] - m); Z += cf[c] * e[c]; }
    float inv = 1.f / Z;
    for (int c = 0; c < 10; ++c) A[h][cq][c] = e[c] * inv;
  }
  __syncthreads();
  if (t < 100) {
    int cq = t / 10, ck = t % 10;
    float v = 0.25f * (A[0][cq][ck] + A[1][cq][ck] + A[2][cq][ck] + A[3][cq][ck]);
    CW[b * 100 + t] = v;
    scw[t] = v;
  }
  for (int i = t; i < 640; i += 256) {
    int cq = i >> 6, dd = i & 63, h = dd >> 4;
    float acc = 0.f;
    for (int ck = 0; ck < 10; ++ck) acc += A[h][cq][ck] * cf[ck] * ve[ck * 64 + dd];
    ctx[cq][dd] = acc;
  }
  __syncthreads();
  for (int i = t; i < 640; i += 256) {
    int cq = i >> 6, dd = i & 63;
    float acc = opb[dd];
    for (int e = 0; e < 64; ++e) acc += ctx[cq][e] * opw[dd * 64 + e];
    AT[(b * 10 + cq) * 64 + dd] = acc;
  }
}

// ---- K c1: conv1 10->32 + relu (tiled, row-pair blocks) -------------------
__global__ __launch_bounds__(256) void k_c1(const float* __restrict__ g,
                                            const float* __restrict__ wt0,
                                            const float* __restrict__ cb,
                                            float* __restrict__ s1) {
  int blk = blockIdx.x, b = blk / 15, pr = blk % 15, oh0 = pr * 2;
  int t = threadIdx.x;
  __shared__ float ins[4][10][34];
  for (int e = t; e < 1360; e += 256) {
    int r = e / 340, rem = e % 340, ic = rem / 34, x = rem % 34;
    int y = oh0 + r - 1, gx = x - 1;
    float v = 0.f;
    if (y >= 0 && y < 30 && gx >= 0 && gx < 30)
      v = g[(size_t)(b * 10 + ic) * 900 + y * 30 + gx];
    ins[r][ic][x] = v;
  }
  __syncthreads();
  int lane = t & 63, ow = lane & 31, rr = lane >> 5;
  int oc0 = __builtin_amdgcn_readfirstlane((t >> 6) * 8);
  float acc[8];
  #pragma unroll
  for (int j = 0; j < 8; ++j) acc[j] = cb[oc0 + j];
  for (int ic = 0; ic < 10; ++ic) {
    #pragma unroll
    for (int ky = 0; ky < 3; ++ky) {
      #pragma unroll
      for (int kx = 0; kx < 3; ++kx) {
        float iv = ins[rr + ky][ic][ow + kx];
        const float* wr = wt0 + (ic * 9 + ky * 3 + kx) * 32 + oc0;
        #pragma unroll
        for (int j = 0; j < 8; ++j) acc[j] = fmaf(iv, wr[j], acc[j]);
      }
    }
  }
  if (ow < 30) {
    #pragma unroll
    for (int j = 0; j < 8; ++j)
      s1[(size_t)(b * 32 + oc0 + j) * 900 + (oh0 + rr) * 30 + ow] = fmaxf(acc[j], 0.f);
  }
}

// ---- K c2: conv2 32->64 + relu + AT add (tiled) ---------------------------
__global__ __launch_bounds__(256) void k_c2(const float* __restrict__ s1,
                                            const float* __restrict__ wt2,
                                            const float* __restrict__ cb,
                                            const float* __restrict__ AT,
                                            const int* __restrict__ idx,
                                            float* __restrict__ comb) {
  int blk = blockIdx.x, b = blk / 15, pr = blk % 15, oh0 = pr * 2;
  int t = threadIdx.x;
  __shared__ float ins[4][32][34];
  for (int e = t; e < 4352; e += 256) {
    int r = e / 1088, rem = e % 1088, ic = rem / 34, x = rem % 34;
    int y = oh0 + r - 1, gx = x - 1;
    float v = 0.f;
    if (y >= 0 && y < 30 && gx >= 0 && gx < 30)
      v = s1[(size_t)(b * 32 + ic) * 900 + y * 30 + gx];
    ins[r][ic][x] = v;
  }
  __syncthreads();
  int lane = t & 63, ow = lane & 31, rr = lane >> 5;
  int oc0 = __builtin_amdgcn_readfirstlane((t >> 6) * 16);
  float acc[16];
  #pragma unroll
  for (int j = 0; j < 16; ++j) acc[j] = cb[oc0 + j];
  for (int ic = 0; ic < 32; ++ic) {
    #pragma unroll
    for (int ky = 0; ky < 3; ++ky) {
      #pragma unroll
      for (int kx = 0; kx < 3; ++kx) {
        float iv = ins[rr + ky][ic][ow + kx];
        const float* wr = wt2 + (ic * 9 + ky * 3 + kx) * 64 + oc0;
        #pragma unroll
        for (int j = 0; j < 16; ++j) acc[j] = fmaf(iv, wr[j], acc[j]);
      }
    }
  }
  if (ow < 30) {
    int c = idx[b * 900 + (oh0 + rr) * 30 + ow];
    const float* at = AT + ((size_t)b * 10 + c) * 64 + oc0;
    #pragma unroll
    for (int j = 0; j < 16; ++j)
      comb[(size_t)(b * 64 + oc0 + j) * 900 + (oh0 + rr) * 30 + ow] =
          fmaxf(acc[j], 0.f) + at[j];
  }
}

// ---- K gfmlp: fused mean-pool + MLP + softmax + argmax --------------------
__global__ void k_gfmlp(const float* __restrict__ comb, const float* __restrict__ l1w,
                        const float* __restrict__ l1b, const float* __restrict__ l2w,
                        const float* __restrict__ l2b, float* __restrict__ out_cm,
                        unsigned char* __restrict__ stash) {
  int b = blockIdx.x, t = threadIdx.x;  // 256
  int wv = t >> 6, lane = t & 63;
  __shared__ float gch[64], hmid[128], lg[100];
  for (int ch = wv; ch < 64; ch += 4) {
    const float* src = comb + ((size_t)b * 64 + ch) * 900;
    float a = 0.f;
    for (int p = lane; p < 900; p += 64) a += src[p];
    for (int o = 32; o; o >>= 1) a += __shfl_down(a, o, 64);
    if (lane == 0) gch[ch] = a * (1.f / 900.f);
  }
  __syncthreads();
  if (t < 128) {
    float acc = l1b[t];
    for (int j = 0; j < 64; ++j) acc += gch[j] * l1w[t * 64 + j];
    hmid[t] = fmaxf(acc, 0.f);
  }
  __syncthreads();
  if (t < 100) {
    float acc = l2b[t];
    for (int j = 0; j < 128; ++j) acc += hmid[j] * l2w[t * 128 + j];
    lg[t] = acc;
  }
  __syncthreads();
  if (t < 10) {
    float m = lg[t * 10]; int am = 0;
    for (int j = 1; j < 10; ++j) {
      float v = lg[t * 10 + j];
      if (v > m) { m = v; am = j; }
    }
    float e[10]; float Z = 0.f;
    for (int j = 0; j < 10; ++j) { e[j] = expf(lg[t * 10 + j] - m); Z += e[j]; }
    float inv = 1.f / Z;
    for (int j = 0; j < 10; ++j) out_cm[(b * 10 + t) * 10 + j] = e[j] * inv;
    ((int*)(stash + (size_t)b * STASH_STRIDE + 3600))[t] = am;
  }
}

// ---- K d1: decoder convT(64->32)+BN+relu, fused 1x1 pred (tiled) ----------
__global__ __launch_bounds__(256) void k_d1(const float* __restrict__ comb,
                                            const float* __restrict__ wt1,
                                            const float* __restrict__ bias1,
                                            const float* __restrict__ w2,
                                            const float* __restrict__ b2,
                                            float* __restrict__ outp) {
  int blk = blockIdx.x, b = blk / 15, pr = blk % 15, oh0 = pr * 2;
  int t = threadIdx.x;
  __shared__ float ins[4][64][34];
  __shared__ float d1s[2][32][32];
  for (int e = t; e < 8704; e += 256) {
    int r = e / 2176, rem = e % 2176, ic = rem / 34, x = rem % 34;
    int y = oh0 + r - 1, gx = x - 1;
    float v = 0.f;
    if (y >= 0 && y < 30 && gx >= 0 && gx < 30)
      v = comb[(size_t)(b * 64 + ic) * 900 + y * 30 + gx];
    ins[r][ic][x] = v;
  }
  __syncthreads();
  int lane = t & 63, ow = lane & 31, rr = lane >> 5;
  int oc0 = __builtin_amdgcn_readfirstlane((t >> 6) * 8);
  float acc[8];
  #pragma unroll
  for (int j = 0; j < 8; ++j) acc[j] = bias1[oc0 + j];
  for (int ic = 0; ic < 64; ++ic) {
    #pragma unroll
    for (int ky = 0; ky < 3; ++ky) {
      #pragma unroll
      for (int kx = 0; kx < 3; ++kx) {
        float iv = ins[rr + ky][ic][ow + kx];
        const float* wr = wt1 + (ic * 9 + ky * 3 + kx) * 32 + oc0;
        #pragma unroll
        for (int j = 0; j < 8; ++j) acc[j] = fmaf(iv, wr[j], acc[j]);
      }
    }
  }
  if (ow < 30) {
    #pragma unroll
    for (int j = 0; j < 8; ++j) d1s[rr][oc0 + j][ow] = fmaxf(acc[j], 0.f);
  }
  __syncthreads();
  for (int e = t; e < 600; e += 256) {
    int r = e / 300, rem = e % 300, o = rem / 30, ow2 = rem % 30;
    float a2 = b2[o];
    #pragma unroll
    for (int ic = 0; ic < 32; ++ic) a2 += d1s[r][ic][ow2] * w2[ic * 10 + o];
    outp[(size_t)(b * 10 + o) * 900 + (oh0 + r) * 30 + ow2] = a2;
  }
}

// ---- K cw: broadcast color_weights [B,900,900] f32 ------------------------
__global__ void k_cw(const unsigned char* __restrict__ stash,
                     float* __restrict__ out2) {
  int blk = blockIdx.x;
  int b = blk / 60, rc = blk % 60;
  int t = threadIdx.x;
  const unsigned char* sl = stash + (size_t)b * STASH_STRIDE;
  const int* sidx = (const int*)sl;
  const float* scw = (const float*)(sl + 3640);
  __shared__ float lut[10][900];
  __shared__ unsigned char cols[900];
  __shared__ float cwb[100];
  for (int i = t; i < 900; i += 256) cols[i] = (unsigned char)sidx[i];
  for (int i = t; i < 100; i += 256) cwb[i] = scw[i];
  __syncthreads();
  for (int i = t; i < 9000; i += 256) {
    int cq = i / 900, p = i % 900;
    lut[cq][p] = cwb[cq * 10 + cols[p]];
  }
  __syncthreads();
  int base = rc * 15;
  for (int i = t; i < 15 * 225; i += 256) {
    int r = i / 225, ch = i % 225;
    int p = base + r;
    int cq = cols[p];
    float4 v = *(const float4*)&lut[cq][ch * 4];
    *(float4*)&out2[(size_t)b * 810000 + (size_t)p * 900 + ch * 4] = v;
  }
}

// ---- K map: one-hot mapped_output f32 -------------------------------------
__global__ void k_map(const unsigned char* __restrict__ stash,
                      float* __restrict__ out4) {
  int b = blockIdx.x, t = threadIdx.x;
  const unsigned char* sl = stash + (size_t)b * STASH_STRIDE;
  const int* sidx = (const int*)sl;
  const int* sncol = (const int*)(sl + 3600);
  __shared__ unsigned char scol[900];
  __shared__ int sn[10];
  for (int i = t; i < 900; i += 256) scol[i] = (unsigned char)sidx[i];
  if (t < 10) sn[t] = sncol[t];
  __syncthreads();
  for (int i = t; i < 9000; i += 256) {
    int ch = i / 900, p = i % 900;
    out4[(size_t)b * 9000 + i] = (sn[scol[p]] == ch) ? 1.0f : 0.0f;
  }
}

extern "C" void kernel_launch(void* const* d_in, const int* in_sizes, int n_in,
                              void* d_out, int out_size, void* d_ws, size_t ws_size,
                              hipStream_t stream) {
  const float* input_grid = (const float*)d_in[0];
  const float* embed      = (const float*)d_in[1];
  const float* in_proj_w  = (const float*)d_in[2];
  const float* in_proj_b  = (const float*)d_in[3];
  const float* out_proj_w = (const float*)d_in[4];
  const float* out_proj_b = (const float*)d_in[5];
  const float* conv1_w    = (const float*)d_in[6];
  const float* conv1_b    = (const float*)d_in[7];
  const float* conv2_w    = (const float*)d_in[8];
  const float* conv2_b    = (const float*)d_in[9];
  const float* lin1_w     = (const float*)d_in[10];
  const float* lin1_b     = (const float*)d_in[11];
  const float* lin2_w     = (const float*)d_in[12];
  const float* lin2_b     = (const float*)d_in[13];
  const float* dec1_w     = (const float*)d_in[14];
  const float* dec1_b     = (const float*)d_in[15];
  const float* bn_g       = (const float*)d_in[16];
  const float* bn_b       = (const float*)d_in[17];
  const float* dec2_w     = (const float*)d_in[18];
  const float* dec2_b     = (const float*)d_in[19];

  // Output regions in f32 ELEMENTS
  float* out      = (float*)d_out;
  float* out_pred = out;                  // 576,000
  float* out_cmap = out + 576000;         // 6,400
  float* out_cw   = out + 582400;         // 51,840,000
  float* out_map  = out + 52422400;       // 576,000

  // Scratch inside out_cw region (dead until k_cw runs). ~22.7 MB used.
  float* cwf   = out_cw;
  float* comb  = cwf;                     // 3,686,400
  float* s1    = cwf + 3686400;           // 1,843,200
  float* AT    = cwf + 5529600;           // 40,960
  float* ve    = cwf + 5570560;           // 640
  float* S     = cwf + 5571200;           // 400
  float* CW    = cwf + 5571600;           // 6,400
  float* wt0   = cwf + 5578000;           // 2,880
  float* wt2   = cwf + 5580880;           // 18,432
  float* wt1   = cwf + 5599312;           // 18,432
  float* bias1 = cwf + 5617744;           // 32
  int*   idx   = (int*)(cwf + 5617776);   // 57,600 -> end 5,675,376 floats
  unsigned char* stash = (unsigned char*)out_map;  // 64 slices x 36000 B (use 4040)

  k_prep_tables<<<159, 256, 0, stream>>>(embed, in_proj_w, in_proj_b,
                                         conv1_w, conv2_w, dec1_w, dec1_b, bn_g, bn_b,
                                         ve, S, wt0, wt2, wt1, bias1);
  k_idxattn<<<B, 256, 0, stream>>>(input_grid, S, ve, out_proj_w, out_proj_b,
                                   idx, CW, AT, stash);
  k_c1<<<B * 15, 256, 0, stream>>>(input_grid, wt0, conv1_b, s1);
  k_c2<<<B * 15, 256, 0, stream>>>(s1, wt2, conv2_b, AT, idx, comb);
  k_gfmlp<<<B, 256, 0, stream>>>(comb, lin1_w, lin1_b, lin2_w, lin2_b,
                                 out_cmap, stash);
  k_d1<<<B * 15, 256, 0, stream>>>(comb, wt1, bias1, dec2_w, dec2_b, out_pred);
  k_cw<<<B * 60, 256, 0, stream>>>(stash, out_cw);
  k_map<<<B, 256, 0, stream>>>(stash, out_map);
}

// Round 10
// 237.687 us; speedup vs baseline: 1.1785x; 1.1785x over previous
//
#include <hip/hip_runtime.h>
#include <cstddef>

#define B 64
#define NC 10
#define L 900
#define STASH_STRIDE 36000  // bytes: one full f32 out_map image slice (9000 floats)

typedef float f32x4 __attribute__((ext_vector_type(4)));

// ---- K prep_tables: block 0 = qkv/score tables; blocks 1.. = weights + cnt
__global__ void k_prep_tables(const float* __restrict__ embed,
                              const float* __restrict__ ipw,
                              const float* __restrict__ ipb,
                              const float* __restrict__ cw1,
                              const float* __restrict__ cw2,
                              const float* __restrict__ dw,
                              const float* __restrict__ db,
                              const float* __restrict__ bng,
                              const float* __restrict__ bnb,
                              float* __restrict__ ve_g, float* __restrict__ S_g,
                              float* __restrict__ wt0, float* __restrict__ wt2,
                              float* __restrict__ wt1, float* __restrict__ bias1,
                              int* __restrict__ cnt) {
  int t = threadIdx.x;
  if (blockIdx.x == 0) {
    __shared__ float emb[640], q[640], k[640];
    for (int i = t; i < 640; i += 256) emb[i] = embed[i];
    __syncthreads();
    for (int row = t; row < 192; row += 256) {
      int which = row >> 6, d = row & 63;
      for (int c = 0; c < 10; ++c) {
        float acc = ipb[row];
        for (int j = 0; j < 64; ++j) acc += emb[c * 64 + j] * ipw[row * 64 + j];
        if (which == 0) q[c * 64 + d] = acc;
        else if (which == 1) k[c * 64 + d] = acc;
        else ve_g[c * 64 + d] = acc;
      }
    }
    __syncthreads();
    for (int i = t; i < 400; i += 256) {
      int h = i / 100, r = i % 100, cq = r / 10, ck = r % 10;
      float acc = 0.f;
      for (int e = 0; e < 16; ++e)
        acc += q[cq * 64 + h * 16 + e] * k[ck * 64 + h * 16 + e];
      S_g[i] = acc * 0.25f;
    }
    return;
  }
  int i = (blockIdx.x - 1) * 256 + t;
  if (i < 2880) {
    int r = i / 32, oc = i % 32;
    wt0[r * 32 + oc] = cw1[oc * 90 + r];
  } else if (i < 2880 + 18432) {
    int e = i - 2880, r = e / 64, oc = e % 64;
    wt2[r * 64 + oc] = cw2[oc * 288 + r];
  } else if (i < 2880 + 18432 + 18432) {
    int e = i - 2880 - 18432, r = e / 32, oc = e % 32;
    int ic = r / 9, kk = r % 9, ky = kk / 3, kx = kk % 3;
    float s = bng[oc] / sqrtf(1.f + 1e-5f);
    wt1[r * 32 + oc] = dw[((ic * 32 + oc) * 3 + (2 - ky)) * 3 + (2 - kx)] * s;
  } else if (i < 39744 + 32) {
    int oc = i - 39744;
    float s = bng[oc] / sqrtf(1.f + 1e-5f);
    bias1[oc] = db[oc] * s + bnb[oc];
  } else if (i < 39776 + B * NC) {
    cnt[i - 39776] = 0;
  }
}

// ---- K idx2: per-pixel argmax -> stash sidx + global histogram ------------
__global__ void k_idx2(const float* __restrict__ g, unsigned char* __restrict__ stash,
                       int* __restrict__ cnt) {
  int i = blockIdx.x * 256 + threadIdx.x;
  if (i >= B * L) return;
  int b = i / L, p = i % L;
  const float* gb = g + (size_t)b * NC * L;
  float best = gb[p]; int bi = 0;
  for (int c = 1; c < NC; ++c) {
    float v = gb[c * L + p];
    if (v > best) { best = v; bi = c; }
  }
  ((int*)(stash + (size_t)b * STASH_STRIDE))[p] = bi;
  atomicAdd(&cnt[b * NC + bi], 1);
}

// ---- K attn: per-image A, CW->stash, ctx, AT ------------------------------
__global__ void k_attn(const float* __restrict__ S, const float* __restrict__ ve,
                       const int* __restrict__ cnt,
                       const float* __restrict__ opw, const float* __restrict__ opb,
                       float* __restrict__ AT, unsigned char* __restrict__ stash) {
  int b = blockIdx.x, t = threadIdx.x;  // 128 threads
  float* scw = (float*)(stash + (size_t)b * STASH_STRIDE + 3640);
  __shared__ float A[4][10][10];
  __shared__ float cf[10];
  __shared__ float ctx[10][64];
  if (t < 10) cf[t] = (float)cnt[b * 10 + t];
  __syncthreads();
  if (t < 40) {
    int h = t / 10, cq = t % 10;
    const float* Sr = S + (h * 10 + cq) * 10;
    float m = -1e30f;
    for (int c = 0; c < 10; ++c) if (cf[c] > 0.f) m = fmaxf(m, Sr[c]);
    float e[10]; float Z = 0.f;
    for (int c = 0; c < 10; ++c) { e[c] = expf(Sr[c] - m); Z += cf[c] * e[c]; }
    float inv = 1.f / Z;
    for (int c = 0; c < 10; ++c) A[h][cq][c] = e[c] * inv;
  }
  __syncthreads();
  if (t < 100) {
    int cq = t / 10, ck = t % 10;
    scw[t] = 0.25f * (A[0][cq][ck] + A[1][cq][ck] + A[2][cq][ck] + A[3][cq][ck]);
  }
  for (int i = t; i < 640; i += 128) {
    int cq = i >> 6, dd = i & 63, h = dd >> 4;
    float acc = 0.f;
    for (int ck = 0; ck < 10; ++ck) acc += A[h][cq][ck] * cf[ck] * ve[ck * 64 + dd];
    ctx[cq][dd] = acc;
  }
  __syncthreads();
  for (int i = t; i < 640; i += 128) {
    int cq = i >> 6, dd = i & 63;
    float acc = opb[dd];
    for (int e = 0; e < 64; ++e) acc += ctx[cq][e] * opw[dd * 64 + e];
    AT[(b * 10 + cq) * 64 + dd] = acc;
  }
}

// ---- K c1: conv1 10->32 + relu (tiled, row-pair blocks) -------------------
__global__ __launch_bounds__(256) void k_c1(const float* __restrict__ g,
                                            const float* __restrict__ wt0,
                                            const float* __restrict__ cb,
                                            float* __restrict__ s1) {
  int blk = blockIdx.x, b = blk / 15, pr = blk % 15, oh0 = pr * 2;
  int t = threadIdx.x;
  __shared__ float ins[4][10][34];
  for (int e = t; e < 1360; e += 256) {
    int r = e / 340, rem = e % 340, ic = rem / 34, x = rem % 34;
    int y = oh0 + r - 1, gx = x - 1;
    float v = 0.f;
    if (y >= 0 && y < 30 && gx >= 0 && gx < 30)
      v = g[(size_t)(b * 10 + ic) * 900 + y * 30 + gx];
    ins[r][ic][x] = v;
  }
  __syncthreads();
  int lane = t & 63, ow = lane & 31, rr = lane >> 5;
  int oc0 = __builtin_amdgcn_readfirstlane((t >> 6) * 8);
  float acc[8];
  #pragma unroll
  for (int j = 0; j < 8; ++j) acc[j] = cb[oc0 + j];
  for (int ic = 0; ic < 10; ++ic) {
    #pragma unroll
    for (int ky = 0; ky < 3; ++ky) {
      #pragma unroll
      for (int kx = 0; kx < 3; ++kx) {
        float iv = ins[rr + ky][ic][ow + kx];
        const float* wr = wt0 + (ic * 9 + ky * 3 + kx) * 32 + oc0;
        #pragma unroll
        for (int j = 0; j < 8; ++j) acc[j] = fmaf(iv, wr[j], acc[j]);
      }
    }
  }
  if (ow < 30) {
    #pragma unroll
    for (int j = 0; j < 8; ++j)
      s1[(size_t)(b * 32 + oc0 + j) * 900 + (oh0 + rr) * 30 + ow] = fmaxf(acc[j], 0.f);
  }
}

// ---- K c2: conv2 32->64 + relu + AT add (tiled; cols from stash) ----------
__global__ __launch_bounds__(256) void k_c2(const float* __restrict__ s1,
                                            const float* __restrict__ wt2,
                                            const float* __restrict__ cb,
                                            const float* __restrict__ AT,
                                            const unsigned char* __restrict__ stash,
                                            float* __restrict__ comb) {
  int blk = blockIdx.x, b = blk / 15, pr = blk % 15, oh0 = pr * 2;
  int t = threadIdx.x;
  __shared__ float ins[4][32][34];
  for (int e = t; e < 4352; e += 256) {
    int r = e / 1088, rem = e % 1088, ic = rem / 34, x = rem % 34;
    int y = oh0 + r - 1, gx = x - 1;
    float v = 0.f;
    if (y >= 0 && y < 30 && gx >= 0 && gx < 30)
      v = s1[(size_t)(b * 32 + ic) * 900 + y * 30 + gx];
    ins[r][ic][x] = v;
  }
  __syncthreads();
  int lane = t & 63, ow = lane & 31, rr = lane >> 5;
  int oc0 = __builtin_amdgcn_readfirstlane((t >> 6) * 16);
  float acc[16];
  #pragma unroll
  for (int j = 0; j < 16; ++j) acc[j] = cb[oc0 + j];
  for (int ic = 0; ic < 32; ++ic) {
    #pragma unroll
    for (int ky = 0; ky < 3; ++ky) {
      #pragma unroll
      for (int kx = 0; kx < 3; ++kx) {
        float iv = ins[rr + ky][ic][ow + kx];
        const float* wr = wt2 + (ic * 9 + ky * 3 + kx) * 64 + oc0;
        #pragma unroll
        for (int j = 0; j < 16; ++j) acc[j] = fmaf(iv, wr[j], acc[j]);
      }
    }
  }
  if (ow < 30) {
    const int* sidx = (const int*)(stash + (size_t)b * STASH_STRIDE);
    int c = sidx[(oh0 + rr) * 30 + ow];
    const float* at = AT + ((size_t)b * 10 + c) * 64 + oc0;
    #pragma unroll
    for (int j = 0; j < 16; ++j)
      comb[(size_t)(b * 64 + oc0 + j) * 900 + (oh0 + rr) * 30 + ow] =
          fmaxf(acc[j], 0.f) + at[j];
  }
}

// ---- K gf3: global mean pool, one wave per (b,oc) -------------------------
__global__ void k_gf3(const float* __restrict__ comb, float* __restrict__ gf) {
  int wid = blockIdx.x * 4 + (threadIdx.x >> 6);  // b*64+oc
  int lane = threadIdx.x & 63;
  const float* src = comb + (size_t)wid * 900;
  float a = 0.f;
  for (int p = lane; p < 900; p += 64) a += src[p];
  for (int o = 32; o; o >>= 1) a += __shfl_down(a, o, 64);
  if (lane == 0) gf[wid] = a * (1.f / 900.f);
}

// ---- K mlp: 64->128->100, softmax + argmax->stash -------------------------
__global__ void k_mlp(const float* __restrict__ gf, const float* __restrict__ l1w,
                      const float* __restrict__ l1b, const float* __restrict__ l2w,
                      const float* __restrict__ l2b, float* __restrict__ out_cm,
                      unsigned char* __restrict__ stash) {
  int b = blockIdx.x, t = threadIdx.x;  // 128
  __shared__ float g[64], hmid[128], lg[100];
  if (t < 64) g[t] = gf[b * 64 + t];
  __syncthreads();
  {
    float acc = l1b[t];
    for (int j = 0; j < 64; ++j) acc += g[j] * l1w[t * 64 + j];
    hmid[t] = fmaxf(acc, 0.f);
  }
  __syncthreads();
  if (t < 100) {
    float acc = l2b[t];
    for (int j = 0; j < 128; ++j) acc += hmid[j] * l2w[t * 128 + j];
    lg[t] = acc;
  }
  __syncthreads();
  if (t < 10) {
    float m = lg[t * 10]; int am = 0;
    for (int j = 1; j < 10; ++j) {
      float v = lg[t * 10 + j];
      if (v > m) { m = v; am = j; }
    }
    float e[10]; float Z = 0.f;
    for (int j = 0; j < 10; ++j) { e[j] = expf(lg[t * 10 + j] - m); Z += e[j]; }
    float inv = 1.f / Z;
    for (int j = 0; j < 10; ++j) out_cm[(b * 10 + t) * 10 + j] = e[j] * inv;
    ((int*)(stash + (size_t)b * STASH_STRIDE + 3600))[t] = am;
  }
}

// ---- K d1: decoder convT(64->32)+BN+relu, fused 1x1 pred (tiled) ----------
__global__ __launch_bounds__(256) void k_d1(const float* __restrict__ comb,
                                            const float* __restrict__ wt1,
                                            const float* __restrict__ bias1,
                                            const float* __restrict__ w2,
                                            const float* __restrict__ b2,
                                            float* __restrict__ outp) {
  int blk = blockIdx.x, b = blk / 15, pr = blk % 15, oh0 = pr * 2;
  int t = threadIdx.x;
  __shared__ float ins[4][64][34];
  __shared__ float d1s[2][32][32];
  for (int e = t; e < 8704; e += 256) {
    int r = e / 2176, rem = e % 2176, ic = rem / 34, x = rem % 34;
    int y = oh0 + r - 1, gx = x - 1;
    float v = 0.f;
    if (y >= 0 && y < 30 && gx >= 0 && gx < 30)
      v = comb[(size_t)(b * 64 + ic) * 900 + y * 30 + gx];
    ins[r][ic][x] = v;
  }
  __syncthreads();
  int lane = t & 63, ow = lane & 31, rr = lane >> 5;
  int oc0 = __builtin_amdgcn_readfirstlane((t >> 6) * 8);
  float acc[8];
  #pragma unroll
  for (int j = 0; j < 8; ++j) acc[j] = bias1[oc0 + j];
  for (int ic = 0; ic < 64; ++ic) {
    #pragma unroll
    for (int ky = 0; ky < 3; ++ky) {
      #pragma unroll
      for (int kx = 0; kx < 3; ++kx) {
        float iv = ins[rr + ky][ic][ow + kx];
        const float* wr = wt1 + (ic * 9 + ky * 3 + kx) * 32 + oc0;
        #pragma unroll
        for (int j = 0; j < 8; ++j) acc[j] = fmaf(iv, wr[j], acc[j]);
      }
    }
  }
  if (ow < 30) {
    #pragma unroll
    for (int j = 0; j < 8; ++j) d1s[rr][oc0 + j][ow] = fmaxf(acc[j], 0.f);
  }
  __syncthreads();
  for (int e = t; e < 600; e += 256) {
    int r = e / 300, rem = e % 300, o = rem / 30, ow2 = rem % 30;
    float a2 = b2[o];
    #pragma unroll
    for (int ic = 0; ic < 32; ++ic) a2 += d1s[r][ic][ow2] * w2[ic * 10 + o];
    outp[(size_t)(b * 10 + o) * 900 + (oh0 + r) * 30 + ow2] = a2;
  }
}

// ---- K cw: broadcast color_weights [B,900,900] f32 (nontemporal stores) ---
__global__ void k_cw(const unsigned char* __restrict__ stash,
                     float* __restrict__ out2) {
  int blk = blockIdx.x;
  int b = blk / 60, rc = blk % 60;
  int t = threadIdx.x;
  const unsigned char* sl = stash + (size_t)b * STASH_STRIDE;
  const int* sidx = (const int*)sl;
  const float* scw = (const float*)(sl + 3640);
  __shared__ float lut[10][900];
  __shared__ unsigned char cols[900];
  __shared__ float cwb[100];
  for (int i = t; i < 900; i += 256) cols[i] = (unsigned char)sidx[i];
  for (int i = t; i < 100; i += 256) cwb[i] = scw[i];
  __syncthreads();
  for (int i = t; i < 9000; i += 256) {
    int cq = i / 900, p = i % 900;
    lut[cq][p] = cwb[cq * 10 + cols[p]];
  }
  __syncthreads();
  int base = rc * 15;
  for (int i = t; i < 15 * 225; i += 256) {
    int r = i / 225, ch = i % 225;
    int p = base + r;
    int cq = cols[p];
    f32x4 v = *(const f32x4*)&lut[cq][ch * 4];
    __builtin_nontemporal_store(v, (f32x4*)&out2[(size_t)b * 810000 + (size_t)p * 900 + ch * 4]);
  }
}

// ---- K map: one-hot mapped_output f32 -------------------------------------
__global__ void k_map(const unsigned char* __restrict__ stash,
                      float* __restrict__ out4) {
  int b = blockIdx.x, t = threadIdx.x;
  const unsigned char* sl = stash + (size_t)b * STASH_STRIDE;
  const int* sidx = (const int*)sl;
  const int* sncol = (const int*)(sl + 3600);
  __shared__ unsigned char scol[900];
  __shared__ int sn[10];
  for (int i = t; i < 900; i += 256) scol[i] = (unsigned char)sidx[i];
  if (t < 10) sn[t] = sncol[t];
  __syncthreads();
  for (int i = t; i < 9000; i += 256) {
    int ch = i / 900, p = i % 900;
    out4[(size_t)b * 9000 + i] = (sn[scol[p]] == ch) ? 1.0f : 0.0f;
  }
}

extern "C" void kernel_launch(void* const* d_in, const int* in_sizes, int n_in,
                              void* d_out, int out_size, void* d_ws, size_t ws_size,
                              hipStream_t stream) {
  const float* input_grid = (const float*)d_in[0];
  const float* embed      = (const float*)d_in[1];
  const float* in_proj_w  = (const float*)d_in[2];
  const float* in_proj_b  = (const float*)d_in[3];
  const float* out_proj_w = (const float*)d_in[4];
  const float* out_proj_b = (const float*)d_in[5];
  const float* conv1_w    = (const float*)d_in[6];
  const float* conv1_b    = (const float*)d_in[7];
  const float* conv2_w    = (const float*)d_in[8];
  const float* conv2_b    = (const float*)d_in[9];
  const float* lin1_w     = (const float*)d_in[10];
  const float* lin1_b     = (const float*)d_in[11];
  const float* lin2_w     = (const float*)d_in[12];
  const float* lin2_b     = (const float*)d_in[13];
  const float* dec1_w     = (const float*)d_in[14];
  const float* dec1_b     = (const float*)d_in[15];
  const float* bn_g       = (const float*)d_in[16];
  const float* bn_b       = (const float*)d_in[17];
  const float* dec2_w     = (const float*)d_in[18];
  const float* dec2_b     = (const float*)d_in[19];

  // Output regions in f32 ELEMENTS
  float* out      = (float*)d_out;
  float* out_pred = out;                  // 576,000
  float* out_cmap = out + 576000;         // 6,400
  float* out_cw   = out + 582400;         // 51,840,000
  float* out_map  = out + 52422400;       // 576,000

  // Scratch inside out_cw region (dead until k_cw runs). ~22.6 MB used.
  float* cwf   = out_cw;
  float* comb  = cwf;                     // 3,686,400
  float* s1    = cwf + 3686400;           // 1,843,200
  float* AT    = cwf + 5529600;           // 40,960
  float* ve    = cwf + 5570560;           // 640
  float* S     = cwf + 5571200;           // 400
  float* gf    = cwf + 5571600;           // 4,096
  float* wt0   = cwf + 5575696;           // 2,880
  float* wt2   = cwf + 5578576;           // 18,432
  float* wt1   = cwf + 5597008;           // 18,432
  float* bias1 = cwf + 5615440;           // 32
  int*   cnt   = (int*)(cwf + 5615472);   // 640
  unsigned char* stash = (unsigned char*)out_map;  // 64 slices x 36000 B (use 4040)

  k_prep_tables<<<159, 256, 0, stream>>>(embed, in_proj_w, in_proj_b,
                                         conv1_w, conv2_w, dec1_w, dec1_b, bn_g, bn_b,
                                         ve, S, wt0, wt2, wt1, bias1, cnt);
  k_idx2<<<(B * L + 255) / 256, 256, 0, stream>>>(input_grid, stash, cnt);
  k_attn<<<B, 128, 0, stream>>>(S, ve, cnt, out_proj_w, out_proj_b, AT, stash);
  k_c1<<<B * 15, 256, 0, stream>>>(input_grid, wt0, conv1_b, s1);
  k_c2<<<B * 15, 256, 0, stream>>>(s1, wt2, conv2_b, AT, stash, comb);
  k_gf3<<<1024, 256, 0, stream>>>(comb, gf);
  k_mlp<<<B, 128, 0, stream>>>(gf, lin1_w, lin1_b, lin2_w, lin2_b, out_cmap, stash);
  k_d1<<<B * 15, 256, 0, stream>>>(comb, wt1, bias1, dec2_w, dec2_b, out_pred);
  k_cw<<<B * 60, 256, 0, stream>>>(stash, out_cw);
  k_map<<<B, 256, 0, stream>>>(stash, out_map);
}

// Round 11
// 179.299 us; speedup vs baseline: 1.5622x; 1.3256x over previous
//
#include <hip/hip_runtime.h>
#include <cstddef>

#define B 64
#define NC 10
#define L 900
#define STASH_STRIDE 36000  // bytes: one full f32 out_map image slice (9000 floats)

typedef float f32x4 __attribute__((ext_vector_type(4)));

// ---- scratch layout (float offsets) ----
#define SCR_COMB   0          // 3,686,400
#define SCR_S1     3686400    // 1,843,200
#define SCR_AT     5529600    // 40,960
#define SCR_VE     5570560    // 640
#define SCR_S      5571200    // 400
#define SCR_WT2    5571600    // 18,432
#define SCR_WT1    5590032    // 18,432
#define SCR_BIAS1  5608464    // 32
#define SCR_GFP    5608496    // 61,440
#define SCR_CNT    5669936    // 640 ints
#define SCR_FLOATS 5670576

// ---- K front: block-specialized independent setup work --------------------
// blocks 0: qkv/score tables | 1..145: wt2/wt1/bias1 | 146..209: per-image
// argmax+hist | 210..1169: conv1
__global__ __launch_bounds__(256) void k_front(
    const float* __restrict__ g, const float* __restrict__ embed,
    const float* __restrict__ ipw, const float* __restrict__ ipb,
    const float* __restrict__ cw1, const float* __restrict__ c1b,
    const float* __restrict__ cw2, const float* __restrict__ dw,
    const float* __restrict__ db, const float* __restrict__ bng,
    const float* __restrict__ bnb,
    float* __restrict__ scr, unsigned char* __restrict__ stash) {
  int bid = blockIdx.x, t = threadIdx.x;
  __shared__ float smem[4352];
  if (bid == 0) {
    float* emb = smem; float* q = smem + 640; float* k = smem + 1280;
    float* ve = scr + SCR_VE; float* S = scr + SCR_S;
    for (int i = t; i < 640; i += 256) emb[i] = embed[i];
    __syncthreads();
    for (int row = t; row < 192; row += 256) {
      int which = row >> 6, d = row & 63;
      for (int c = 0; c < 10; ++c) {
        float acc = ipb[row];
        for (int j = 0; j < 64; ++j) acc += emb[c * 64 + j] * ipw[row * 64 + j];
        if (which == 0) q[c * 64 + d] = acc;
        else if (which == 1) k[c * 64 + d] = acc;
        else ve[c * 64 + d] = acc;
      }
    }
    __syncthreads();
    for (int i = t; i < 400; i += 256) {
      int h = i / 100, r = i % 100, cq = r / 10, ck = r % 10;
      float acc = 0.f;
      for (int e = 0; e < 16; ++e)
        acc += q[cq * 64 + h * 16 + e] * k[ck * 64 + h * 16 + e];
      S[i] = acc * 0.25f;
    }
  } else if (bid <= 145) {
    int i = (bid - 1) * 256 + t;
    if (i < 18432) {
      int r = i / 64, oc = i % 64;
      scr[SCR_WT2 + r * 64 + oc] = cw2[oc * 288 + r];
    } else if (i < 36864) {
      int e = i - 18432, r = e / 32, oc = e % 32;
      int ic = r / 9, kk = r % 9, ky = kk / 3, kx = kk % 3;
      float s = bng[oc] / sqrtf(1.f + 1e-5f);
      scr[SCR_WT1 + r * 32 + oc] = dw[((ic * 32 + oc) * 3 + (2 - ky)) * 3 + (2 - kx)] * s;
    } else if (i < 36896) {
      int oc = i - 36864;
      float s = bng[oc] / sqrtf(1.f + 1e-5f);
      scr[SCR_BIAS1 + oc] = db[oc] * s + bnb[oc];
    }
  } else if (bid <= 209) {
    int b = bid - 146;
    int* hist = (int*)smem;
    int* cnt = (int*)(scr + SCR_CNT);
    if (t < 10) hist[t] = 0;
    __syncthreads();
    const float* gb = g + (size_t)b * NC * L;
    int* sidx = (int*)(stash + (size_t)b * STASH_STRIDE);
    for (int p = t; p < L; p += 256) {
      float best = gb[p]; int bi = 0;
      for (int c = 1; c < NC; ++c) {
        float v = gb[c * L + p];
        if (v > best) { best = v; bi = c; }
      }
      sidx[p] = bi;
      atomicAdd(&hist[bi], 1);
    }
    __syncthreads();
    if (t < 10) cnt[b * NC + t] = hist[t];
  } else {
    int blk = bid - 210, b = blk / 15, pr = blk % 15, oh0 = pr * 2;
    float* ins = smem;          // [4][10][34] = 1360
    float* ws = smem + 1360;    // 2880 raw conv1_w [oc][ic][3][3]
    float* s1 = scr + SCR_S1;
    for (int i = t; i < 2880; i += 256) ws[i] = cw1[i];
    for (int e = t; e < 1360; e += 256) {
      int r = e / 340, rem = e % 340, ic = rem / 34, x = rem % 34;
      int y = oh0 + r - 1, gx = x - 1;
      float v = 0.f;
      if (y >= 0 && y < 30 && gx >= 0 && gx < 30)
        v = g[(size_t)(b * 10 + ic) * 900 + y * 30 + gx];
      ins[(r * 10 + ic) * 34 + x] = v;
    }
    __syncthreads();
    int lane = t & 63, ow = lane & 31, rr = lane >> 5;
    int oc0 = __builtin_amdgcn_readfirstlane((t >> 6) * 8);
    float acc[8];
    #pragma unroll
    for (int j = 0; j < 8; ++j) acc[j] = c1b[oc0 + j];
    for (int ic = 0; ic < 10; ++ic) {
      #pragma unroll
      for (int ky = 0; ky < 3; ++ky) {
        #pragma unroll
        for (int kx = 0; kx < 3; ++kx) {
          float iv = ins[((rr + ky) * 10 + ic) * 34 + ow + kx];
          #pragma unroll
          for (int j = 0; j < 8; ++j)
            acc[j] = fmaf(iv, ws[((oc0 + j) * 10 + ic) * 9 + ky * 3 + kx], acc[j]);
        }
      }
    }
    if (ow < 30) {
      #pragma unroll
      for (int j = 0; j < 8; ++j)
        s1[(size_t)(b * 32 + oc0 + j) * 900 + (oh0 + rr) * 30 + ow] = fmaxf(acc[j], 0.f);
    }
  }
}

// ---- K attn: per-image A, CW->stash, ctx, AT ------------------------------
__global__ void k_attn(const float* __restrict__ S, const float* __restrict__ ve,
                       const int* __restrict__ cnt,
                       const float* __restrict__ opw, const float* __restrict__ opb,
                       float* __restrict__ AT, unsigned char* __restrict__ stash) {
  int b = blockIdx.x, t = threadIdx.x;  // 128 threads
  float* scw = (float*)(stash + (size_t)b * STASH_STRIDE + 3640);
  __shared__ float A[4][10][10];
  __shared__ float cf[10];
  __shared__ float ctx[10][64];
  if (t < 10) cf[t] = (float)cnt[b * 10 + t];
  __syncthreads();
  if (t < 40) {
    int h = t / 10, cq = t % 10;
    const float* Sr = S + (h * 10 + cq) * 10;
    float m = -1e30f;
    for (int c = 0; c < 10; ++c) if (cf[c] > 0.f) m = fmaxf(m, Sr[c]);
    float e[10]; float Z = 0.f;
    for (int c = 0; c < 10; ++c) { e[c] = expf(Sr[c] - m); Z += cf[c] * e[c]; }
    float inv = 1.f / Z;
    for (int c = 0; c < 10; ++c) A[h][cq][c] = e[c] * inv;
  }
  __syncthreads();
  if (t < 100) {
    int cq = t / 10, ck = t % 10;
    scw[t] = 0.25f * (A[0][cq][ck] + A[1][cq][ck] + A[2][cq][ck] + A[3][cq][ck]);
  }
  for (int i = t; i < 640; i += 128) {
    int cq = i >> 6, dd = i & 63, h = dd >> 4;
    float acc = 0.f;
    for (int ck = 0; ck < 10; ++ck) acc += A[h][cq][ck] * cf[ck] * ve[ck * 64 + dd];
    ctx[cq][dd] = acc;
  }
  __syncthreads();
  for (int i = t; i < 640; i += 128) {
    int cq = i >> 6, dd = i & 63;
    float acc = opb[dd];
    for (int e = 0; e < 64; ++e) acc += ctx[cq][e] * opw[dd * 64 + e];
    AT[(b * 10 + cq) * 64 + dd] = acc;
  }
}

// ---- K c2: conv2 32->64 + relu + AT add + gf partial reduce ---------------
__global__ __launch_bounds__(256) void k_c2(const float* __restrict__ scr_s1,
                                            const float* __restrict__ wt2,
                                            const float* __restrict__ cb,
                                            const float* __restrict__ AT,
                                            const unsigned char* __restrict__ stash,
                                            float* __restrict__ comb,
                                            float* __restrict__ gfp) {
  int blk = blockIdx.x, b = blk / 15, pr = blk % 15, oh0 = pr * 2;
  int t = threadIdx.x;
  __shared__ float ins[4][32][34];
  for (int e = t; e < 4352; e += 256) {
    int r = e / 1088, rem = e % 1088, ic = rem / 34, x = rem % 34;
    int y = oh0 + r - 1, gx = x - 1;
    float v = 0.f;
    if (y >= 0 && y < 30 && gx >= 0 && gx < 30)
      v = scr_s1[(size_t)(b * 32 + ic) * 900 + y * 30 + gx];
    ins[r][ic][x] = v;
  }
  __syncthreads();
  int lane = t & 63, ow = lane & 31, rr = lane >> 5;
  int oc0 = __builtin_amdgcn_readfirstlane((t >> 6) * 16);
  float acc[16];
  #pragma unroll
  for (int j = 0; j < 16; ++j) acc[j] = cb[oc0 + j];
  for (int ic = 0; ic < 32; ++ic) {
    #pragma unroll
    for (int ky = 0; ky < 3; ++ky) {
      #pragma unroll
      for (int kx = 0; kx < 3; ++kx) {
        float iv = ins[rr + ky][ic][ow + kx];
        const float* wr = wt2 + (ic * 9 + ky * 3 + kx) * 64 + oc0;
        #pragma unroll
        for (int j = 0; j < 16; ++j) acc[j] = fmaf(iv, wr[j], acc[j]);
      }
    }
  }
  float outv[16];
  if (ow < 30) {
    const int* sidx = (const int*)(stash + (size_t)b * STASH_STRIDE);
    int c = sidx[(oh0 + rr) * 30 + ow];
    const float* at = AT + ((size_t)b * 10 + c) * 64 + oc0;
    #pragma unroll
    for (int j = 0; j < 16; ++j) {
      outv[j] = fmaxf(acc[j], 0.f) + at[j];
      comb[(size_t)(b * 64 + oc0 + j) * 900 + (oh0 + rr) * 30 + ow] = outv[j];
    }
  } else {
    #pragma unroll
    for (int j = 0; j < 16; ++j) outv[j] = 0.f;
  }
  #pragma unroll
  for (int j = 0; j < 16; ++j) {
    float v = outv[j];
    for (int o = 32; o; o >>= 1) v += __shfl_down(v, o, 64);
    if (lane == 0) gfp[(b * 15 + pr) * 64 + oc0 + j] = v;
  }
}

// ---- K back: block-specialized mlp | dec1+pred | cw -----------------------
// blocks 0..63: mlp | 64..1023: d1 | 1024..: cw (if present in grid)
__global__ __launch_bounds__(256) void k_back(
    const float* __restrict__ scr,
    const float* __restrict__ l1w, const float* __restrict__ l1b,
    const float* __restrict__ l2w, const float* __restrict__ l2b,
    const float* __restrict__ w2, const float* __restrict__ b2,
    float* __restrict__ out_pred, float* __restrict__ out_cm,
    float* __restrict__ out_cw2, unsigned char* __restrict__ stash) {
  int bid = blockIdx.x, t = threadIdx.x;
  __shared__ float smem[10880];
  if (bid < 64) {
    int b = bid;
    float* gfl = smem; float* hmid = smem + 64; float* lg = smem + 192;
    const float* gfp = scr + SCR_GFP;
    if (t < 64) {
      float a = 0.f;
      for (int pr = 0; pr < 15; ++pr) a += gfp[(b * 15 + pr) * 64 + t];
      gfl[t] = a * (1.f / 900.f);
    }
    __syncthreads();
    if (t < 128) {
      float acc = l1b[t];
      for (int j = 0; j < 64; ++j) acc += gfl[j] * l1w[t * 64 + j];
      hmid[t] = fmaxf(acc, 0.f);
    }
    __syncthreads();
    if (t < 100) {
      float acc = l2b[t];
      for (int j = 0; j < 128; ++j) acc += hmid[j] * l2w[t * 128 + j];
      lg[t] = acc;
    }
    __syncthreads();
    if (t < 10) {
      float m = lg[t * 10]; int am = 0;
      for (int j = 1; j < 10; ++j) {
        float v = lg[t * 10 + j];
        if (v > m) { m = v; am = j; }
      }
      float e[10]; float Z = 0.f;
      for (int j = 0; j < 10; ++j) { e[j] = expf(lg[t * 10 + j] - m); Z += e[j]; }
      float inv = 1.f / Z;
      for (int j = 0; j < 10; ++j) out_cm[(b * 10 + t) * 10 + j] = e[j] * inv;
      ((int*)(stash + (size_t)b * STASH_STRIDE + 3600))[t] = am;
    }
  } else if (bid < 1024) {
    int blk = bid - 64, b = blk / 15, pr = blk % 15, oh0 = pr * 2;
    float* ins = smem;            // [4][64][34] = 8704
    float* d1s = smem + 8704;     // [2][32][32] = 2048
    const float* comb = scr + SCR_COMB;
    const float* wt1 = scr + SCR_WT1;
    const float* bias1 = scr + SCR_BIAS1;
    for (int e = t; e < 8704; e += 256) {
      int r = e / 2176, rem = e % 2176, ic = rem / 34, x = rem % 34;
      int y = oh0 + r - 1, gx = x - 1;
      float v = 0.f;
      if (y >= 0 && y < 30 && gx >= 0 && gx < 30)
        v = comb[(size_t)(b * 64 + ic) * 900 + y * 30 + gx];
      ins[(r * 64 + ic) * 34 + x] = v;
    }
    __syncthreads();
    int lane = t & 63, ow = lane & 31, rr = lane >> 5;
    int oc0 = __builtin_amdgcn_readfirstlane((t >> 6) * 8);
    float acc[8];
    #pragma unroll
    for (int j = 0; j < 8; ++j) acc[j] = bias1[oc0 + j];
    for (int ic = 0; ic < 64; ++ic) {
      #pragma unroll
      for (int ky = 0; ky < 3; ++ky) {
        #pragma unroll
        for (int kx = 0; kx < 3; ++kx) {
          float iv = ins[((rr + ky) * 64 + ic) * 34 + ow + kx];
          const float* wr = wt1 + (ic * 9 + ky * 3 + kx) * 32 + oc0;
          #pragma unroll
          for (int j = 0; j < 8; ++j) acc[j] = fmaf(iv, wr[j], acc[j]);
        }
      }
    }
    if (ow < 30) {
      #pragma unroll
      for (int j = 0; j < 8; ++j) d1s[(rr * 32 + oc0 + j) * 32 + ow] = fmaxf(acc[j], 0.f);
    }
    __syncthreads();
    for (int e = t; e < 600; e += 256) {
      int r = e / 300, rem = e % 300, o = rem / 30, ow2 = rem % 30;
      float a2 = b2[o];
      #pragma unroll
      for (int ic = 0; ic < 32; ++ic) a2 += d1s[(r * 32 + ic) * 32 + ow2] * w2[ic * 10 + o];
      out_pred[(size_t)(b * 10 + o) * 900 + (oh0 + r) * 30 + ow2] = a2;
    }
  } else {
    int blk = bid - 1024, b = blk / 60, rc = blk % 60;
    float* lut = smem;                                   // [10][900]
    float* cwb = smem + 9000;                            // 100
    unsigned char* cols = (unsigned char*)(smem + 9100); // 900 B
    const unsigned char* sl = stash + (size_t)b * STASH_STRIDE;
    const int* sidx = (const int*)sl;
    const float* scw = (const float*)(sl + 3640);
    for (int i = t; i < 900; i += 256) cols[i] = (unsigned char)sidx[i];
    for (int i = t; i < 100; i += 256) cwb[i] = scw[i];
    __syncthreads();
    for (int i = t; i < 9000; i += 256) {
      int cq = i / 900, p = i % 900;
      lut[cq * 900 + p] = cwb[cq * 10 + cols[p]];
    }
    __syncthreads();
    int base = rc * 15;
    for (int i = t; i < 15 * 225; i += 256) {
      int r = i / 225, ch = i % 225;
      int p = base + r;
      int cq = cols[p];
      f32x4 v = *(const f32x4*)&lut[cq * 900 + ch * 4];
      __builtin_nontemporal_store(v, (f32x4*)&out_cw2[(size_t)b * 810000 + (size_t)p * 900 + ch * 4]);
    }
  }
}

// ---- K cw (fallback only): broadcast color_weights ------------------------
__global__ void k_cw(const unsigned char* __restrict__ stash,
                     float* __restrict__ out2) {
  int blk = blockIdx.x;
  int b = blk / 60, rc = blk % 60;
  int t = threadIdx.x;
  const unsigned char* sl = stash + (size_t)b * STASH_STRIDE;
  const int* sidx = (const int*)sl;
  const float* scw = (const float*)(sl + 3640);
  __shared__ float lut[10][900];
  __shared__ unsigned char cols[900];
  __shared__ float cwb[100];
  for (int i = t; i < 900; i += 256) cols[i] = (unsigned char)sidx[i];
  for (int i = t; i < 100; i += 256) cwb[i] = scw[i];
  __syncthreads();
  for (int i = t; i < 9000; i += 256) {
    int cq = i / 900, p = i % 900;
    lut[cq][p] = cwb[cq * 10 + cols[p]];
  }
  __syncthreads();
  int base = rc * 15;
  for (int i = t; i < 15 * 225; i += 256) {
    int r = i / 225, ch = i % 225;
    int p = base + r;
    int cq = cols[p];
    f32x4 v = *(const f32x4*)&lut[cq][ch * 4];
    __builtin_nontemporal_store(v, (f32x4*)&out2[(size_t)b * 810000 + (size_t)p * 900 + ch * 4]);
  }
}

// ---- K map: one-hot mapped_output f32 -------------------------------------
__global__ void k_map(const unsigned char* __restrict__ stash,
                      float* __restrict__ out4) {
  int b = blockIdx.x, t = threadIdx.x;
  const unsigned char* sl = stash + (size_t)b * STASH_STRIDE;
  const int* sidx = (const int*)sl;
  const int* sncol = (const int*)(sl + 3600);
  __shared__ unsigned char scol[900];
  __shared__ int sn[10];
  for (int i = t; i < 900; i += 256) scol[i] = (unsigned char)sidx[i];
  if (t < 10) sn[t] = sncol[t];
  __syncthreads();
  for (int i = t; i < 9000; i += 256) {
    int ch = i / 900, p = i % 900;
    out4[(size_t)b * 9000 + i] = (sn[scol[p]] == ch) ? 1.0f : 0.0f;
  }
}

extern "C" void kernel_launch(void* const* d_in, const int* in_sizes, int n_in,
                              void* d_out, int out_size, void* d_ws, size_t ws_size,
                              hipStream_t stream) {
  const float* input_grid = (const float*)d_in[0];
  const float* embed      = (const float*)d_in[1];
  const float* in_proj_w  = (const float*)d_in[2];
  const float* in_proj_b  = (const float*)d_in[3];
  const float* out_proj_w = (const float*)d_in[4];
  const float* out_proj_b = (const float*)d_in[5];
  const float* conv1_w    = (const float*)d_in[6];
  const float* conv1_b    = (const float*)d_in[7];
  const float* conv2_w    = (const float*)d_in[8];
  const float* conv2_b    = (const float*)d_in[9];
  const float* lin1_w     = (const float*)d_in[10];
  const float* lin1_b     = (const float*)d_in[11];
  const float* lin2_w     = (const float*)d_in[12];
  const float* lin2_b     = (const float*)d_in[13];
  const float* dec1_w     = (const float*)d_in[14];
  const float* dec1_b     = (const float*)d_in[15];
  const float* bn_g       = (const float*)d_in[16];
  const float* bn_b       = (const float*)d_in[17];
  const float* dec2_w     = (const float*)d_in[18];
  const float* dec2_b     = (const float*)d_in[19];

  // Output regions in f32 ELEMENTS
  float* out      = (float*)d_out;
  float* out_pred = out;                  // 576,000
  float* out_cmap = out + 576000;         // 6,400
  float* out_cw   = out + 582400;         // 51,840,000
  float* out_map  = out + 52422400;       // 576,000

  // Scratch: prefer d_ws (enables cw overlap in k_back); fall back to the
  // dead out_cw region with cw as a separate later launch.
  bool ws_ok = ws_size >= (size_t)SCR_FLOATS * 4;
  float* scr = ws_ok ? (float*)d_ws : out_cw;
  unsigned char* stash = (unsigned char*)out_map;  // 64 slices x 36000 B (use 4040)

  k_front<<<1170, 256, 0, stream>>>(input_grid, embed, in_proj_w, in_proj_b,
                                    conv1_w, conv1_b, conv2_w, dec1_w, dec1_b,
                                    bn_g, bn_b, scr, stash);
  k_attn<<<B, 128, 0, stream>>>(scr + SCR_S, scr + SCR_VE, (int*)(scr + SCR_CNT),
                                out_proj_w, out_proj_b, scr + SCR_AT, stash);
  k_c2<<<960, 256, 0, stream>>>(scr + SCR_S1, scr + SCR_WT2, conv2_b,
                                scr + SCR_AT, stash, scr + SCR_COMB, scr + SCR_GFP);
  k_back<<<ws_ok ? 4864 : 1024, 256, 0, stream>>>(scr, lin1_w, lin1_b, lin2_w, lin2_b,
                                                  dec2_w, dec2_b, out_pred, out_cmap,
                                                  out_cw, stash);
  if (!ws_ok) k_cw<<<B * 60, 256, 0, stream>>>(stash, out_cw);
  k_map<<<B, 256, 0, stream>>>(stash, out_map);
}